// Round 1
// baseline (220.193 us; speedup 1.0000x reference)
//
#include <hip/hip_runtime.h>
#include <cstdint>
#include <cstddef>

typedef int int4v __attribute__((ext_vector_type(4)));

#define DEVI __device__ __forceinline__

DEVI void load_lds16(const void* g, void* l) {
  __builtin_amdgcn_global_load_lds(
      (const __attribute__((address_space(1))) void*)g,
      (__attribute__((address_space(3))) void*)l, 16, 0, 0);
}

// ---- pack int32 -> int8, linear (4 elems/thread) ----
__global__ __launch_bounds__(256) void pack_i8(const int* __restrict__ src,
                                               signed char* __restrict__ dst,
                                               int n4) {
  int i = blockIdx.x * 256 + threadIdx.x;
  if (i >= n4) return;
  int4v v = ((const int4v*)src)[i];
  int p = (v.x & 255) | ((v.y & 255) << 8) | ((v.z & 255) << 16) | (v.w << 24);
  ((int*)dst)[i] = p;
}

// ---- pack + transpose: w[K][N] int32 -> wT[N][K] int8, 64x64 LDS tiles ----
__global__ __launch_bounds__(256) void pack_wT(const int* __restrict__ w,
                                               signed char* __restrict__ wT,
                                               int K, int N) {
  __shared__ signed char t[64][68];
  int n0 = blockIdx.x * 64, k0 = blockIdx.y * 64;
  int tr = threadIdx.x >> 6, tc = threadIdx.x & 63;
#pragma unroll
  for (int i = 0; i < 16; ++i) {
    int r = i * 4 + tr;  // k index
    t[r][tc] = (signed char)w[(size_t)(k0 + r) * N + n0 + tc];
  }
  __syncthreads();
#pragma unroll
  for (int i = 0; i < 16; ++i) {
    int r = i * 4 + tr;  // n index
    wT[(size_t)(n0 + r) * K + k0 + tc] = t[tc][r];
  }
}

// ---- i8 GEMM: C[M,N] = A[M,K] * BT[N,K]^T, MFMA 16x16x64 i8 ----
// EPI 0: relu+requant -> int8 outQ ; EPI 1: f32 alpha*acc + bias_f -> outF
template <int EPI>
__global__ __launch_bounds__(256) void gemm_i8(
    const signed char* __restrict__ A, const signed char* __restrict__ BT,
    int M, int N, int K, const int* __restrict__ bias_i,
    const float* __restrict__ alphaP, const float* __restrict__ betaP,
    const float* __restrict__ bias_f, signed char* __restrict__ outQ,
    float* __restrict__ outF) {
  constexpr int BK = 128;  // bytes per row; 2 MFMA K-steps of 64
  __shared__ signed char As[128 * BK];  // 16 KB
  __shared__ signed char Bs[128 * BK];  // 16 KB

  const int tid = threadIdx.x;
  const int wid = tid >> 6;
  const int lane = tid & 63;
  const int wr = wid >> 1, wc = wid & 1;  // 2x2 wave grid, 64x64 each
  const int l16 = lane & 15, l4 = lane >> 4;
  const int rowBase = blockIdx.y * 128;
  const int colBase = blockIdx.x * 128;

  int4v acc[4][4] = {};

  for (int kt = 0; kt < K; kt += BK) {
    // stage A,B tiles: global_load_lds width 16; LDS dest is linear
    // (wave-uniform base + lane*16); swizzle applied on the GLOBAL source:
    // LDS slot s of row r receives global slot s ^ (r&7).
#pragma unroll
    for (int c = 0; c < 4; ++c) {
      int base = (c * 4 + wid) * 1024;  // per-wave 1KB chunks
      int off = base + lane * 16;
      int r = off >> 7;                       // tile row (128B rows)
      int gs = ((off >> 4) & 7) ^ (r & 7);    // pre-swizzled global slot
      load_lds16(A + (size_t)(rowBase + r) * K + kt + gs * 16, As + base);
      load_lds16(BT + (size_t)(colBase + r) * K + kt + gs * 16, Bs + base);
    }
    __syncthreads();  // compiler drains vmcnt before barrier
#pragma unroll
    for (int kk = 0; kk < 2; ++kk) {
      int4v a[4], b[4];
#pragma unroll
      for (int mi = 0; mi < 4; ++mi) {
        int r = wr * 64 + mi * 16 + l16;
        int slot = (kk * 4 + l4) ^ (r & 7);  // inverse of source swizzle
        a[mi] = *(const int4v*)(As + r * BK + slot * 16);
      }
#pragma unroll
      for (int ni = 0; ni < 4; ++ni) {
        int r = wc * 64 + ni * 16 + l16;
        int slot = (kk * 4 + l4) ^ (r & 7);
        b[ni] = *(const int4v*)(Bs + r * BK + slot * 16);
      }
#pragma unroll
      for (int mi = 0; mi < 4; ++mi)
#pragma unroll
        for (int ni = 0; ni < 4; ++ni)
          acc[mi][ni] = __builtin_amdgcn_mfma_i32_16x16x64_i8(
              a[mi], b[ni], acc[mi][ni], 0, 0, 0);
    }
    __syncthreads();  // protect LDS from next stage
  }

  // ---- epilogue; C/D frag: col = lane&15, row = (lane>>4)*4 + j ----
  const float alpha = alphaP[0];
  if (EPI == 0) {
    const float beta = betaP[0];
#pragma unroll
    for (int mi = 0; mi < 4; ++mi) {
      int row = rowBase + wr * 64 + mi * 16 + l4 * 4;
#pragma unroll
      for (int ni = 0; ni < 4; ++ni) {
        int col = colBase + wc * 64 + ni * 16 + l16;
        float bterm = (float)bias_i[col] * beta;
#pragma unroll
        for (int j = 0; j < 4; ++j) {
          float h = (float)acc[mi][ni][j] * alpha + bterm;
          h = fmaxf(h, 0.f);
          h = rintf(h);          // numpy round-half-even
          h = fminf(h, 127.f);
          outQ[(size_t)(row + j) * N + col] = (signed char)h;
        }
      }
    }
  } else {
#pragma unroll
    for (int mi = 0; mi < 4; ++mi) {
      int row = rowBase + wr * 64 + mi * 16 + l4 * 4;
#pragma unroll
      for (int ni = 0; ni < 4; ++ni) {
        int col = colBase + wc * 64 + ni * 16 + l16;
        float bv = bias_f[col];
#pragma unroll
        for (int j = 0; j < 4; ++j) {
          outF[(size_t)(row + j) * N + col] = (float)acc[mi][ni][j] * alpha + bv;
        }
      }
    }
  }
}

extern "C" void kernel_launch(void* const* d_in, const int* in_sizes, int n_in,
                              void* d_out, int out_size, void* d_ws,
                              size_t ws_size, hipStream_t stream) {
  const int M = 16384, H = 1024, I = 4096;  // B*S=16384
  const int* hidden = (const int*)d_in[0];
  const int* w_fc = (const int*)d_in[1];
  const int* b_fc = (const int*)d_in[2];
  const float* alpha_fc = (const float*)d_in[3];
  const float* beta_fc = (const float*)d_in[4];
  const int* w_proj = (const int*)d_in[5];
  const float* b_proj = (const float*)d_in[6];
  const float* alpha_proj = (const float*)d_in[7];
  float* out = (float*)d_out;

  // workspace layout (88 MB total)
  signed char* hq = (signed char*)d_ws;        // [M][I]  64 MB
  signed char* aP = hq + (size_t)M * I;        // [M][H]  16 MB
  signed char* wfcT = aP + (size_t)M * H;      // [I][H]   4 MB  (w_fc^T)
  signed char* wpT = wfcT + (size_t)I * H;     // [H][I]   4 MB  (w_proj^T)

  pack_i8<<<(M * H / 4 + 255) / 256, 256, 0, stream>>>(hidden, aP, M * H / 4);
  pack_wT<<<dim3(I / 64, H / 64), 256, 0, stream>>>(w_fc, wfcT, H, I);
  pack_wT<<<dim3(H / 64, I / 64), 256, 0, stream>>>(w_proj, wpT, I, H);

  gemm_i8<0><<<dim3(I / 128, M / 128), 256, 0, stream>>>(
      aP, wfcT, M, I, H, b_fc, alpha_fc, beta_fc, nullptr, hq, nullptr);
  gemm_i8<1><<<dim3(H / 128, M / 128), 256, 0, stream>>>(
      hq, wpT, M, H, I, nullptr, alpha_proj, nullptr, b_proj, nullptr, out);
}

// Round 2
// 178.894 us; speedup vs baseline: 1.2309x; 1.2309x over previous
//
#include <hip/hip_runtime.h>
#include <cstdint>
#include <cstddef>

typedef int int4v __attribute__((ext_vector_type(4)));
typedef signed char schar;

#define DEVI __device__ __forceinline__

DEVI void load_lds16(const void* g, void* l) {
  __builtin_amdgcn_global_load_lds(
      (const __attribute__((address_space(1))) void*)g,
      (__attribute__((address_space(3))) void*)l, 16, 0, 0);
}

#define BAR() __builtin_amdgcn_s_barrier()
#define LGKM0()                                                     \
  do {                                                              \
    asm volatile("s_waitcnt lgkmcnt(0)" ::: "memory");              \
    __builtin_amdgcn_sched_barrier(0);                              \
  } while (0)
#define VMW(n)                                                      \
  do {                                                              \
    asm volatile("s_waitcnt vmcnt(" #n ")" ::: "memory");           \
    __builtin_amdgcn_sched_barrier(0);                              \
  } while (0)

// ---- pack int32 -> int8, linear (4 elems/thread) ----
__global__ __launch_bounds__(256) void pack_i8(const int* __restrict__ src,
                                               signed char* __restrict__ dst,
                                               int n4) {
  int i = blockIdx.x * 256 + threadIdx.x;
  if (i >= n4) return;
  int4v v = ((const int4v*)src)[i];
  int p = (v.x & 255) | ((v.y & 255) << 8) | ((v.z & 255) << 16) | (v.w << 24);
  ((int*)dst)[i] = p;
}

// ---- pack + transpose: w[K][N] int32 -> wT[N][K] int8, 64x64 LDS tiles ----
__global__ __launch_bounds__(256) void pack_wT(const int* __restrict__ w,
                                               signed char* __restrict__ wT,
                                               int K, int N) {
  __shared__ signed char t[64][68];
  int n0 = blockIdx.x * 64, k0 = blockIdx.y * 64;
  int tr = threadIdx.x >> 6, tc = threadIdx.x & 63;
#pragma unroll
  for (int i = 0; i < 16; ++i) {
    int r = i * 4 + tr;  // k index
    t[r][tc] = (signed char)w[(size_t)(k0 + r) * N + n0 + tc];
  }
  __syncthreads();
#pragma unroll
  for (int i = 0; i < 16; ++i) {
    int r = i * 4 + tr;  // n index
    wT[(size_t)(n0 + r) * K + k0 + tc] = t[tc][r];
  }
}

// ---- 256x256 8-phase i8 GEMM: C[M,N] = A[M,K] * BT[N,K]^T ----
// 8 waves (2Mx4N), per-wave 128x64 out, BK=128 bytes (2 K-steps of 16x16x64).
// LDS: A[2][256][128] at 0, B[2][256][128] at 65536 (128 KiB dynamic).
// Phase schedule per K-tile T (buffers: c = T&1, o = c^1):
//   P0: ds A(qm0)+B(qn0) | stage A-half0 of T+1 -> buf o | MFMA quad(0,0)
//   P1: ds B(qn1)        | stage A-half1 of T+1 -> buf o | MFMA quad(0,1)
//   P2: ds A(qm1)        | stage B-half0 of T+2 -> buf c | MFMA quad(1,0)
//   P3:                  | stage B-half1 of T+2 -> buf c | MFMA quad(1,1)
//       vmcnt(4) before final barrier (leaves B of T+2 in flight).
template <int EPI>
__global__ __launch_bounds__(512, 2) void gemm8(
    const schar* __restrict__ A, const schar* __restrict__ BT,
    int M, int N, int K, const int* __restrict__ bias_i,
    const float* __restrict__ alphaP, const float* __restrict__ betaP,
    const float* __restrict__ bias_f, schar* __restrict__ outQ,
    float* __restrict__ outF) {
  extern __shared__ schar lds[];
  constexpr int ATILE = 32768;  // 256 rows x 128 B

  const int tid = threadIdx.x;
  const int wid = tid >> 6, lane = tid & 63;
  const int wr = wid >> 2, wc = wid & 3;
  const int l16 = lane & 15, l4 = lane >> 4;

  // XCD-bijective block swizzle (nwg % 8 == 0 for both GEMMs)
  const int gx = gridDim.x;
  const int nwg = gx * gridDim.y;
  const int bid = blockIdx.y * gx + blockIdx.x;
  const int swz = (bid & 7) * (nwg >> 3) + (bid >> 3);
  const int rowBase = (swz / gx) * 256;
  const int colBase = (swz % gx) * 256;

  const int NT = K >> 7;

  // staging: 2 load_lds16 per half-tile per thread; instr i covers
  // off = i*8192 + tid*16 within the 16 KB half. Pre-swizzled global slot.
  const int off0 = tid * 16, off1 = 8192 + tid * 16;
  const int rl0 = off0 >> 7, rl1 = off1 >> 7;
  const int gs0 = ((off0 >> 4) & 7) ^ (rl0 & 7);
  const int gs1 = ((off1 >> 4) & 7) ^ (rl1 & 7);
  const schar* gA0 = A + (size_t)(rowBase + rl0) * K + gs0 * 16;
  const schar* gA1 = A + (size_t)(rowBase + rl1) * K + gs1 * 16;
  const schar* gB0 = BT + (size_t)(colBase + rl0) * K + gs0 * 16;
  const schar* gB1 = BT + (size_t)(colBase + rl1) * K + gs1 * 16;
  const size_t hstep = (size_t)128 * K;
  const int wb = wid * 1024;  // wave-uniform LDS chunk base

  auto stA = [&](int buf, int t, int h) {
    schar* d = lds + buf * ATILE + h * 16384 + wb;
    load_lds16(gA0 + (size_t)t * 128 + (size_t)h * hstep, d);
    load_lds16(gA1 + (size_t)t * 128 + (size_t)h * hstep, d + 8192);
  };
  auto stB = [&](int buf, int t, int h) {
    schar* d = lds + 2 * ATILE + buf * ATILE + h * 16384 + wb;
    load_lds16(gB0 + (size_t)t * 128 + (size_t)h * hstep, d);
    load_lds16(gB1 + (size_t)t * 128 + (size_t)h * hstep, d + 8192);
  };

  int4v acc[8][4] = {};
  int4v a[4][2], b0[2][2], b1[2][2];

  // ds_read fragment loads; row&7 == l16&7, so swizzle slot is lane-only.
#define LDA(QM, Ab)                                                         \
  do {                                                                      \
    _Pragma("unroll") for (int mi = 0; mi < 4; ++mi)                        \
        _Pragma("unroll") for (int kk = 0; kk < 2; ++kk) a[mi][kk] =        \
        *(const int4v*)((Ab) + (wr * 128 + (QM)*64 + mi * 16 + l16) * 128 + \
                        (((kk * 4) + l4) ^ (l16 & 7)) * 16);                \
  } while (0)
#define LDB(B, QN, Bb)                                                       \
  do {                                                                       \
    _Pragma("unroll") for (int ni = 0; ni < 2; ++ni)                         \
        _Pragma("unroll") for (int kk = 0; kk < 2; ++kk) (B)[ni][kk] =       \
        *(const int4v*)((Bb) +                                               \
                        (wc * 64 + ((QN)*2 + ni) * 16 + l16) * 128 +         \
                        (((kk * 4) + l4) ^ (l16 & 7)) * 16);                 \
  } while (0)
#define MMQ(QM, QN, B)                                                       \
  do {                                                                       \
    __builtin_amdgcn_s_setprio(1);                                           \
    _Pragma("unroll") for (int kk = 0; kk < 2; ++kk)                         \
        _Pragma("unroll") for (int mi = 0; mi < 4; ++mi)                     \
            _Pragma("unroll") for (int ni = 0; ni < 2; ++ni)                 \
                acc[(QM)*4 + mi][(QN)*2 + ni] =                              \
        __builtin_amdgcn_mfma_i32_16x16x64_i8(                               \
            a[mi][kk], (B)[ni][kk], acc[(QM)*4 + mi][(QN)*2 + ni], 0, 0, 0); \
    __builtin_amdgcn_s_setprio(0);                                           \
  } while (0)

  // prologue: tile0 fully, tile1 B halves; collective vmcnt(4)+barrier
  stA(0, 0, 0);
  stA(0, 0, 1);
  stB(0, 0, 0);
  stB(0, 0, 1);
  if (NT > 1) {
    stB(1, 1, 0);
    stB(1, 1, 1);
    VMW(4);
  } else {
    VMW(0);
  }
  BAR();

  for (int T = 0; T < NT; ++T) {
    const int cb = T & 1, ob = cb ^ 1;
    const schar* Ac = lds + cb * ATILE;
    const schar* Bc = lds + 2 * ATILE + cb * ATILE;

    // P0
    LDA(0, Ac);
    LDB(b0, 0, Bc);
    if (T + 1 < NT) stA(ob, T + 1, 0);
    BAR();
    LGKM0();
    MMQ(0, 0, b0);
    BAR();
    // P1
    LDB(b1, 1, Bc);
    if (T + 1 < NT) stA(ob, T + 1, 1);
    BAR();
    LGKM0();
    MMQ(0, 1, b1);
    BAR();
    // P2
    LDA(1, Ac);
    if (T + 2 < NT) stB(cb, T + 2, 0);
    BAR();
    LGKM0();
    MMQ(1, 0, b0);
    BAR();
    // P3
    if (T + 2 < NT) stB(cb, T + 2, 1);
    BAR();
    MMQ(1, 1, b1);
    if (T + 2 < NT) {
      VMW(4);
    } else if (T + 1 < NT) {
      VMW(0);
    }
    BAR();
  }

  // ---- epilogue; C/D frag: col = lane&15, row = (lane>>4)*4 + j ----
  const float alpha = alphaP[0];
  if (EPI == 0) {
    const float beta = betaP[0];
#pragma unroll
    for (int MI = 0; MI < 8; ++MI) {
      int row = rowBase + wr * 128 + MI * 16 + l4 * 4;
#pragma unroll
      for (int NI = 0; NI < 4; ++NI) {
        int col = colBase + wc * 64 + NI * 16 + l16;
        float bt = (float)bias_i[col] * beta;
#pragma unroll
        for (int j = 0; j < 4; ++j) {
          float h = (float)acc[MI][NI][j] * alpha + bt;
          h = fmaxf(h, 0.f);
          h = rintf(h);  // numpy round-half-even
          h = fminf(h, 127.f);
          outQ[(size_t)(row + j) * N + col] = (schar)h;
        }
      }
    }
  } else {
#pragma unroll
    for (int MI = 0; MI < 8; ++MI) {
      int row = rowBase + wr * 128 + MI * 16 + l4 * 4;
#pragma unroll
      for (int NI = 0; NI < 4; ++NI) {
        int col = colBase + wc * 64 + NI * 16 + l16;
        float bv = bias_f[col];
#pragma unroll
        for (int j = 0; j < 4; ++j) {
          outF[(size_t)(row + j) * N + col] =
              (float)acc[MI][NI][j] * alpha + bv;
        }
      }
    }
  }
#undef LDA
#undef LDB
#undef MMQ
}

extern "C" void kernel_launch(void* const* d_in, const int* in_sizes, int n_in,
                              void* d_out, int out_size, void* d_ws,
                              size_t ws_size, hipStream_t stream) {
  const int M = 16384, H = 1024, I = 4096;  // B*S = 16384
  const int* hidden = (const int*)d_in[0];
  const int* w_fc = (const int*)d_in[1];
  const int* b_fc = (const int*)d_in[2];
  const float* alpha_fc = (const float*)d_in[3];
  const float* beta_fc = (const float*)d_in[4];
  const int* w_proj = (const int*)d_in[5];
  const float* b_proj = (const float*)d_in[6];
  const float* alpha_proj = (const float*)d_in[7];
  float* out = (float*)d_out;

  // workspace layout (88 MB total)
  signed char* hq = (signed char*)d_ws;      // [M][I]  64 MB
  signed char* aP = hq + (size_t)M * I;      // [M][H]  16 MB
  signed char* wfcT = aP + (size_t)M * H;    // [I][H]   4 MB (w_fc^T)
  signed char* wpT = wfcT + (size_t)I * H;   // [H][I]   4 MB (w_proj^T)

  hipFuncSetAttribute((const void*)gemm8<0>,
                      hipFuncAttributeMaxDynamicSharedMemorySize, 131072);
  hipFuncSetAttribute((const void*)gemm8<1>,
                      hipFuncAttributeMaxDynamicSharedMemorySize, 131072);

  pack_i8<<<(M * H / 4 + 255) / 256, 256, 0, stream>>>(hidden, aP, M * H / 4);
  pack_wT<<<dim3(I / 64, H / 64), 256, 0, stream>>>(w_fc, wfcT, H, I);
  pack_wT<<<dim3(H / 64, I / 64), 256, 0, stream>>>(w_proj, wpT, I, H);

  gemm8<0><<<dim3(I / 256, M / 256), 512, 131072, stream>>>(
      aP, wfcT, M, I, H, b_fc, alpha_fc, beta_fc, nullptr, hq, nullptr);
  gemm8<1><<<dim3(H / 256, M / 256), 512, 131072, stream>>>(
      hq, wpT, M, H, I, nullptr, alpha_proj, nullptr, b_proj, nullptr, out);
}